// Round 13
// baseline (100.893 us; speedup 1.0000x reference)
//
#include <hip/hip_runtime.h>
#include <stdint.h>

// Conv2d as implicit GEMM, bf16 MFMA.
// R13: R12 structure (256x128 blocks, 4 waves, BK=32, 48KB LDS, 2 blocks/CU,
// one barrier/tile, zero-conflict paired-row LDS) with 32x32x16 MFMA
// (2495 vs 2075 TF ceiling, half the MFMA instructions, same LDS traffic).
// GEMM: M=100352, N=256, K=1152 (k=(kh*3+kw)*128+ci). 36 K-tiles. Grid 784.

#define CIN   128
#define HW_   56
#define CO_   256
#define KSZ   1152
#define IMGHW 3136
#define HP    58
#define NT    36
#define BUFSZ 24576        // A [128 lines][128B] @0 (16KB) + B [64 lines][128B] @16K
#define XT_BYTES ((size_t)32 * HP * HP * CIN * 2)   // 27,557,888
#define WP_BYTES ((size_t)CO_ * KSZ * 2)            // 589,824
#define WS_NEED  (XT_BYTES + WP_BYTES)
#define XBLKS    (32 * HP)
#define PBLKS    ((CO_ * KSZ) / 256)

typedef __attribute__((ext_vector_type(8)))  __bf16 bf16x8;
typedef __attribute__((ext_vector_type(4)))  float  f32x4;
typedef __attribute__((ext_vector_type(16))) float  f32x16;
typedef __attribute__((ext_vector_type(8)))  unsigned short ushort8;

__device__ __forceinline__ unsigned short f2bf(float f) {
    unsigned int u = __float_as_uint(f);
    u += 0x7fffu + ((u >> 16) & 1u);   // RNE
    return (unsigned short)(u >> 16);
}

__device__ __forceinline__ void gl2lds16(const void* g, void* l) {
    __builtin_amdgcn_global_load_lds(
        (const __attribute__((address_space(1))) void*)g,
        (__attribute__((address_space(3))) void*)l, 16, 0, 0);
}

// ---- fused prep: xform (blocks 0..XBLKS-1) + weight pack (rest)
__global__ __launch_bounds__(256)
void prep(const float* __restrict__ x, unsigned short* __restrict__ xt,
          const float* __restrict__ w, unsigned short* __restrict__ wp) {
    const int t = threadIdx.x;
    if (blockIdx.x >= XBLKS) {                  // ---- weight pack [co][k]
        int idx = (blockIdx.x - XBLKS) * 256 + t;
        int co = idx / KSZ;
        int k  = idx - co * KSZ;
        wp[idx] = f2bf(w[(co * CIN + (k & 127)) * 9 + (k >> 7)]);
        return;
    }
    const int nb = blockIdx.x;
    const int n  = nb / HP;
    const int hp = nb - n * HP;
    unsigned short* orow = xt + ((size_t)n * HP + hp) * (HP * CIN);

    if (hp == 0 || hp == HP - 1) {
        for (int i = t; i < (HP * CIN) / 8; i += 256)
            ((ushort8*)orow)[i] = (ushort8){0, 0, 0, 0, 0, 0, 0, 0};
        return;
    }
    const int h = hp - 1;
    __shared__ ushort2 T[CIN][31];
    {
        const int ci = t >> 1, part = t & 1;
        const float* src = x + (((size_t)n * CIN + ci) * IMGHW + h * HW_ + part * 28);
        #pragma unroll
        for (int j = 0; j < 7; ++j) {
            float4 v = *(const float4*)(src + 4 * j);
            T[ci][part * 14 + 2 * j]     = (ushort2){f2bf(v.x), f2bf(v.y)};
            T[ci][part * 14 + 2 * j + 1] = (ushort2){f2bf(v.z), f2bf(v.w)};
        }
    }
    __syncthreads();
    const int wpg = t >> 4, cig = t & 15;
    const int ci0 = cig * 8;
    for (int wp_ = wpg; wp_ < HP; wp_ += 16) {
        ushort8 v = (ushort8){0, 0, 0, 0, 0, 0, 0, 0};
        const int w_ = wp_ - 1;
        if ((unsigned)w_ < (unsigned)HW_) {
            #pragma unroll
            for (int e = 0; e < 8; ++e) {
                ushort2 p = T[ci0 + e][w_ >> 1];
                v[e] = (w_ & 1) ? p.y : p.x;
            }
        }
        *(ushort8*)(orow + wp_ * CIN + ci0) = v;
    }
}

// ---- main conv: 256x128 block, BK=32, 4 waves (2m x 2n), wave 128x64,
// 32x32x16 MFMA: wave = 4mt x 2nt tiles of 32x32, 2 k-steps of 16.
__global__ __launch_bounds__(256, 2)
void conv13(const unsigned short* __restrict__ xt,
            const unsigned short* __restrict__ wpk,
            float* __restrict__ out)
{
    __shared__ __align__(16) char lds[2][BUFSZ];   // 48 KiB -> 2 blocks/CU

    const int tid  = threadIdx.x;
    const int lane = tid & 63;
    const int wid  = tid >> 6;

    int bid = blockIdx.x;
    int flat = (bid & 7) * 98 + (bid >> 3);     // XCD swizzle, 784 = 8*98 bijective
    const int mt_  = flat >> 1;                 // pair shares A-panel
    const int n0   = (flat & 1) << 7;
    const int m0   = mt_ << 8;

    // ---- staging (R12-identical, measured 0 conflicts) ----
    const int lc = (tid & 7) ^ ((tid >> 3) & 7);
    uint32_t aoff[4], boff[2];
    #pragma unroll
    for (int p = 0; p < 4; ++p) {
        int m = m0 + ((p * 32 + (tid >> 3)) << 1) + (lc >> 2);
        int n = m / IMGHW;
        int rem = m - n * IMGHW;
        int h = rem / HW_;
        int w = rem - h * HW_;
        aoff[p] = (uint32_t)((((n * HP + h) * HP + w) << 8) + ((lc & 3) << 4));
    }
    #pragma unroll
    for (int q = 0; q < 2; ++q) {
        int co = n0 + ((q * 32 + (tid >> 3)) << 1) + (lc >> 2);
        boff[q] = (uint32_t)(co * (KSZ * 2) + ((lc & 3) << 4));
    }

    // ---- 32x32 fragment read offsets ----
    // lane holds op[row = lane&31][k = ks*16 + (lane>>5)*8 + e]; row-pair line,
    // logical chunk = (parity<<2)|(ks*2+(lane>>5)), phys = lc ^ (line&7).
    const int l31h = (lane & 31) >> 1;          // line-within-tile 0..15
    const int par  = lane & 1;
    const int khg  = lane >> 5;                 // k-group 0/1
    const int physA0 = (((par << 2) | (0 + khg)) ^ (l31h & 7)) << 4;   // ks=0
    const int physA1 = (((par << 2) | (2 + khg)) ^ (l31h & 7)) << 4;   // ks=1
    const int wm0 = (wid >> 1) << 7;            // 0 / 128
    const int wn0 = (wid & 1) << 6;             // 0 / 64
    const int aB = ((wm0 >> 1) + l31h) * 128;            // + mt*2048 + physA
    const int bB = 16384 + ((wn0 >> 1) + l31h) * 128;    // + nt*2048 + physA

    const char* xtc = (const char*)xt;
    const char* wpc = (const char*)wpk;

    f32x16 acc[4][2];
    #pragma unroll
    for (int i = 0; i < 4; ++i)
        #pragma unroll
        for (int j = 0; j < 2; ++j)
            #pragma unroll
            for (int r = 0; r < 16; ++r)
                acc[i][j][r] = 0.f;

    auto STAGE = [&](int t) {                   // 6 gl2lds -> buf t&1 (R12-identical)
        char* L = &lds[t & 1][0];
        int tap = t >> 2;
        int kh = (tap * 11) >> 5;               // tap/3 for tap<9
        int kw = tap - kh * 3;
        uint32_t asl = (uint32_t)(((kh * HP + kw) << 8) + ((t & 3) << 6));
        uint32_t bsl = (uint32_t)(t << 6);
        #pragma unroll
        for (int p = 0; p < 4; ++p)
            gl2lds16(xtc + aoff[p] + asl, L + p * 4096 + tid * 16);
        #pragma unroll
        for (int q = 0; q < 2; ++q)
            gl2lds16(wpc + boff[q] + bsl, L + 16384 + q * 4096 + tid * 16);
    };

    // ---- prologue ----
    STAGE(0);
    asm volatile("s_waitcnt vmcnt(0)" ::: "memory");
    __builtin_amdgcn_s_barrier();

    #pragma unroll 1
    for (int t = 0; t < NT; ++t) {
        if (t + 1 < NT) STAGE(t + 1);

        const char* L = &lds[t & 1][0];
        ushort8 a[4][2], b[2][2];
        #pragma unroll
        for (int nt = 0; nt < 2; ++nt) {
            b[nt][0] = *(const ushort8*)(L + bB + nt * 2048 + physA0);
            b[nt][1] = *(const ushort8*)(L + bB + nt * 2048 + physA1);
        }
        #pragma unroll
        for (int mt = 0; mt < 4; ++mt) {
            a[mt][0] = *(const ushort8*)(L + aB + mt * 2048 + physA0);
            a[mt][1] = *(const ushort8*)(L + aB + mt * 2048 + physA1);
        }

        __builtin_amdgcn_s_setprio(1);
        #pragma unroll
        for (int mt = 0; mt < 4; ++mt)
            #pragma unroll
            for (int nt = 0; nt < 2; ++nt) {
                acc[mt][nt] = __builtin_amdgcn_mfma_f32_32x32x16_bf16(
                    __builtin_bit_cast(bf16x8, b[nt][0]),
                    __builtin_bit_cast(bf16x8, a[mt][0]),
                    acc[mt][nt], 0, 0, 0);
                acc[mt][nt] = __builtin_amdgcn_mfma_f32_32x32x16_bf16(
                    __builtin_bit_cast(bf16x8, b[nt][1]),
                    __builtin_bit_cast(bf16x8, a[mt][1]),
                    acc[mt][nt], 0, 0, 0);
            }
        __builtin_amdgcn_s_setprio(0);

        if (t + 1 < NT) asm volatile("s_waitcnt vmcnt(0)" ::: "memory");
        __builtin_amdgcn_s_barrier();
    }

    // ---- epilogue: D col = lane&31 (m, contiguous), row = (r&3)+8*(r>>2)+4*khg (co)
    #pragma unroll
    for (int mt = 0; mt < 4; ++mt) {
        int m = m0 + wm0 + mt * 32 + (lane & 31);
        int n = m / IMGHW;
        int hwr = m - n * IMGHW;
        uint32_t basem = (uint32_t)(n * (CO_ * IMGHW) + hwr);
        #pragma unroll
        for (int nt = 0; nt < 2; ++nt) {
            int co0 = n0 + wn0 + nt * 32 + 4 * khg;
            #pragma unroll
            for (int r = 0; r < 16; ++r) {
                int co = co0 + (r & 3) + 8 * (r >> 2);
                out[basem + (uint32_t)co * IMGHW] = acc[mt][nt][r];
            }
        }
    }
}

// ================= fallback (round-1 kernel, used if ws too small) ==========
#define BM    64
#define BK    32
#define NSTEP 36
#define LDSP  40

template<bool PACKED>
__global__ __launch_bounds__(256, 2)
void conv_fb(const float* __restrict__ x,
             const float* __restrict__ wraw,
             const unsigned short* __restrict__ wp,
             float* __restrict__ out)
{
    __shared__ __align__(16) unsigned short Al[2][BM][LDSP];
    __shared__ __align__(16) unsigned short Bl[2][CO_][LDSP];

    const int tid  = threadIdx.x;
    const int lane = tid & 63;
    const int wid  = tid >> 6;

    const int mb    = blockIdx.x;
    const int n_img = mb / 49;
    const int hw0   = (mb - n_img * 49) * BM;

    const int mm = lane;
    const int hw = hw0 + mm;
    const int h  = hw / HW_;
    const int w_ = hw - h * HW_;

    const int bco  = tid >> 2;
    const int bkkg = tid & 3;

    float   aPF[8];
    ushort8 bPF[4];

    auto loadA = [&](int step) {
        int khkw = step >> 2;
        int kh = khkw / 3, kw = khkw - (khkw / 3) * 3;
        int ci0 = (step & 3) * BK + wid * 8;
        int ih = h + kh - 1, iw = w_ + kw - 1;
        bool valid = ((unsigned)ih < (unsigned)HW_) && ((unsigned)iw < (unsigned)HW_);
        const float* px = x + (((size_t)(n_img * CIN + ci0) * HW_ + ih) * HW_ + iw);
        #pragma unroll
        for (int e = 0; e < 8; ++e)
            aPF[e] = valid ? px[e * IMGHW] : 0.f;
    };
    auto writeA = [&](int buf) {
        ushort8 v;
        #pragma unroll
        for (int e = 0; e < 8; ++e) v[e] = f2bf(aPF[e]);
        *(ushort8*)&Al[buf][mm][wid * 8] = v;
    };
    auto loadB = [&](int step) {
        if (PACKED) {
            int k0 = step * BK;
            #pragma unroll
            for (int r = 0; r < 4; ++r)
                bPF[r] = *(const ushort8*)&wp[(r * 64 + bco) * KSZ + k0 + bkkg * 8];
        } else {
            int khkw = step >> 2;
            int ci0 = (step & 3) * BK + bkkg * 8;
            #pragma unroll
            for (int r = 0; r < 4; ++r) {
                int co = r * 64 + bco;
                ushort8 v;
                #pragma unroll
                for (int e = 0; e < 8; ++e)
                    v[e] = f2bf(wraw[(co * CIN + ci0 + e) * 9 + khkw]);
                bPF[r] = v;
            }
        }
    };
    auto writeB = [&](int buf) {
        #pragma unroll
        for (int r = 0; r < 4; ++r)
            *(ushort8*)&Bl[buf][r * 64 + bco][bkkg * 8] = bPF[r];
    };

    f32x4 acc[4][4];
    #pragma unroll
    for (int i = 0; i < 4; ++i)
        #pragma unroll
        for (int j = 0; j < 4; ++j)
            acc[i][j] = (f32x4){0.f, 0.f, 0.f, 0.f};

    const int frow = lane & 15;
    const int fk   = (lane >> 4) * 8;

    loadA(0); loadB(0);
    writeA(0); writeB(0);
    __syncthreads();

    for (int s = 0; s < NSTEP; ++s) {
        const int cur = s & 1;
        if (s + 1 < NSTEP) { loadA(s + 1); loadB(s + 1); }

        ushort8 aF[4], bF[4];
        #pragma unroll
        for (int i = 0; i < 4; ++i)
            aF[i] = *(const ushort8*)&Bl[cur][wid * 64 + i * 16 + frow][fk];
        #pragma unroll
        for (int j = 0; j < 4; ++j)
            bF[j] = *(const ushort8*)&Al[cur][j * 16 + frow][fk];

        #pragma unroll
        for (int i = 0; i < 4; ++i)
            #pragma unroll
            for (int j = 0; j < 4; ++j)
                acc[i][j] = __builtin_amdgcn_mfma_f32_16x16x32_bf16(
                    __builtin_bit_cast(bf16x8, aF[i]),
                    __builtin_bit_cast(bf16x8, bF[j]),
                    acc[i][j], 0, 0, 0);

        if (s + 1 < NSTEP) { writeA(cur ^ 1); writeB(cur ^ 1); }
        __syncthreads();
    }

    float* ob = out + (size_t)n_img * (CO_ * IMGHW) + hw0;
    #pragma unroll
    for (int i = 0; i < 4; ++i) {
        int co0 = wid * 64 + i * 16 + (lane >> 4) * 4;
        #pragma unroll
        for (int j = 0; j < 4; ++j) {
            int mcol = j * 16 + (lane & 15);
            #pragma unroll
            for (int q = 0; q < 4; ++q)
                ob[(size_t)(co0 + q) * IMGHW + mcol] = acc[i][j][q];
        }
    }
}

extern "C" void kernel_launch(void* const* d_in, const int* in_sizes, int n_in,
                              void* d_out, int out_size, void* d_ws, size_t ws_size,
                              hipStream_t stream) {
    (void)in_sizes; (void)n_in; (void)out_size;
    const float* x  = (const float*)d_in[0];
    const float* wt = (const float*)d_in[1];
    float* out = (float*)d_out;

    if (ws_size >= WS_NEED) {
        unsigned short* xt  = (unsigned short*)d_ws;
        unsigned short* wpk = (unsigned short*)((char*)d_ws + XT_BYTES);
        prep<<<XBLKS + PBLKS, 256, 0, stream>>>(x, xt, wt, wpk);
        conv13<<<784, 256, 0, stream>>>(xt, wpk, out);
    } else {
        conv_fb<false><<<100352 / BM, 256, 0, stream>>>(x, wt, nullptr, out);
    }
}

// Round 14
// 92.524 us; speedup vs baseline: 1.0905x; 1.0905x over previous
//
#include <hip/hip_runtime.h>
#include <stdint.h>

// Conv2d as implicit GEMM, bf16 MFMA.
// R14: R12 structure (256x128 blocks, 4 waves, BK=32, one barrier/tile,
// zero-conflict paired-row A layout) with B LOADED GLOBAL->REG from a
// fragment-contiguous pack (L2-resident, 1KB coalesced per load, 1-tile
// register prefetch). A-only LDS (32KB dbuf). Grid 784, 2 blocks/CU.
// GEMM: M=100352, N=256, K=1152 (k=(kh*3+kw)*128+ci). 36 K-tiles.

#define CIN   128
#define HW_   56
#define CO_   256
#define KSZ   1152
#define IMGHW 3136
#define HP    58
#define NT    36
#define XT_BYTES ((size_t)32 * HP * HP * CIN * 2)   // 27,557,888
#define WP_BYTES ((size_t)CO_ * KSZ * 2)            // 589,824
#define WS_NEED  (XT_BYTES + WP_BYTES)
#define XBLKS    (32 * HP)
#define PBLKS    ((CO_ * KSZ) / 256)

typedef __attribute__((ext_vector_type(8)))  __bf16 bf16x8;
typedef __attribute__((ext_vector_type(4)))  float  f32x4;
typedef __attribute__((ext_vector_type(8)))  unsigned short ushort8;

__device__ __forceinline__ unsigned short f2bf(float f) {
    unsigned int u = __float_as_uint(f);
    u += 0x7fffu + ((u >> 16) & 1u);   // RNE
    return (unsigned short)(u >> 16);
}

__device__ __forceinline__ void gl2lds16(const void* g, void* l) {
    __builtin_amdgcn_global_load_lds(
        (const __attribute__((address_space(1))) void*)g,
        (__attribute__((address_space(3))) void*)l, 16, 0, 0);
}

// ---- fused prep: xform (blocks 0..XBLKS-1) + fragment-contiguous weight pack.
// Pack: wp2[(((t*16 + cog)*64 + lane)*8 + e] = bf16(W[co][k]) with
//   co = cog*16 + (lane&15),  k = t*32 + (lane>>4)*8 + e,  W[co][k] from
//   w[(co*128 + (k&127))*9 + (k>>7)]  (k = khkw*128 + ci ordering).
__global__ __launch_bounds__(256)
void prep(const float* __restrict__ x, unsigned short* __restrict__ xt,
          const float* __restrict__ w, unsigned short* __restrict__ wp2) {
    const int t = threadIdx.x;
    if (blockIdx.x >= XBLKS) {                  // ---- weight pack
        int o = (blockIdx.x - XBLKS) * 256 + t;
        int e    = o & 7;
        int lane = (o >> 3) & 63;
        int cog  = (o >> 9) & 15;
        int tt   = o >> 13;                     // 0..35
        int co = cog * 16 + (lane & 15);
        int k  = tt * 32 + (lane >> 4) * 8 + e;
        wp2[o] = f2bf(w[(co * CIN + (k & 127)) * 9 + (k >> 7)]);
        return;
    }
    const int nb = blockIdx.x;
    const int n  = nb / HP;
    const int hp = nb - n * HP;
    unsigned short* orow = xt + ((size_t)n * HP + hp) * (HP * CIN);

    if (hp == 0 || hp == HP - 1) {
        for (int i = t; i < (HP * CIN) / 8; i += 256)
            ((ushort8*)orow)[i] = (ushort8){0, 0, 0, 0, 0, 0, 0, 0};
        return;
    }
    const int h = hp - 1;
    __shared__ ushort2 T[CIN][31];
    {
        const int ci = t >> 1, part = t & 1;
        const float* src = x + (((size_t)n * CIN + ci) * IMGHW + h * HW_ + part * 28);
        #pragma unroll
        for (int j = 0; j < 7; ++j) {
            float4 v = *(const float4*)(src + 4 * j);
            T[ci][part * 14 + 2 * j]     = (ushort2){f2bf(v.x), f2bf(v.y)};
            T[ci][part * 14 + 2 * j + 1] = (ushort2){f2bf(v.z), f2bf(v.w)};
        }
    }
    __syncthreads();
    const int wpg = t >> 4, cig = t & 15;
    const int ci0 = cig * 8;
    for (int wp_ = wpg; wp_ < HP; wp_ += 16) {
        ushort8 v = (ushort8){0, 0, 0, 0, 0, 0, 0, 0};
        const int w_ = wp_ - 1;
        if ((unsigned)w_ < (unsigned)HW_) {
            #pragma unroll
            for (int e = 0; e < 8; ++e) {
                ushort2 p = T[ci0 + e][w_ >> 1];
                v[e] = (w_ & 1) ? p.y : p.x;
            }
        }
        *(ushort8*)(orow + wp_ * CIN + ci0) = v;
    }
}

// ---- main conv: 256x128 block, BK=32, 4 waves (2m x 2n), wave 128x64
__global__ __launch_bounds__(256, 2)
void conv14(const unsigned short* __restrict__ xt,
            const unsigned short* __restrict__ wp2,
            float* __restrict__ out)
{
    __shared__ __align__(16) char lds[2][16384];   // A only, 32 KiB

    const int tid  = threadIdx.x;
    const int lane = tid & 63;
    const int wid  = tid >> 6;

    int bid = blockIdx.x;
    int flat = (bid & 7) * 98 + (bid >> 3);     // XCD swizzle, 784 = 8*98 bijective
    const int mt_ = flat >> 1;                  // pair shares A-panel
    const int n0  = (flat & 1) << 7;
    const int m0  = mt_ << 8;

    // ---- A staging (R12-identical paired-row layout, measured 0 conflicts) ----
    const int lc = (tid & 7) ^ ((tid >> 3) & 7);
    uint32_t aoff[4];
    #pragma unroll
    for (int p = 0; p < 4; ++p) {
        int m = m0 + ((p * 32 + (tid >> 3)) << 1) + (lc >> 2);
        int n = m / IMGHW;
        int rem = m - n * IMGHW;
        int h = rem / HW_;
        int w = rem - h * HW_;
        aoff[p] = (uint32_t)((((n * HP + h) * HP + w) << 8) + ((lc & 3) << 4));
    }

    // ---- A fragment read offsets (R12-identical) ----
    const int fr = lane & 15, fg = lane >> 4;
    const int cp = (((fr & 1) << 2) | fg) ^ ((fr >> 1) & 7);
    const int wm0 = (wid >> 1) << 7;            // 0 / 128
    const int wn0 = (wid & 1) << 6;             // 0 / 64
    const int aB = (((wm0 >> 1) + (fr >> 1)) << 7) + (cp << 4);   // + mf*1024

    // ---- B fragment-contiguous global base ----
    const int nfgB = (n0 + wn0) >> 4;           // wave's co-group base (0..15)
    const unsigned short* wpb = wp2 + (size_t)lane * 8;

    const char* xtc = (const char*)xt;

    f32x4 acc[8][4];
    #pragma unroll
    for (int i = 0; i < 8; ++i)
        #pragma unroll
        for (int j = 0; j < 4; ++j)
            acc[i][j] = (f32x4){0.f, 0.f, 0.f, 0.f};

    ushort8 b0r[4], b1r[4];

    auto STAGE = [&](int t) {                   // 4 gl2lds -> buf t&1 (A only)
        char* L = &lds[t & 1][0];
        int tap = t >> 2;
        int kh = (tap * 11) >> 5;               // tap/3 for tap<9
        int kw = tap - kh * 3;
        uint32_t asl = (uint32_t)(((kh * HP + kw) << 8) + ((t & 3) << 6));
        #pragma unroll
        for (int p = 0; p < 4; ++p)
            gl2lds16(xtc + aoff[p] + asl, L + p * 4096 + tid * 16);
    };

    #define LOADB(B_, t) do { \
        _Pragma("unroll") for (int nf_ = 0; nf_ < 4; ++nf_) \
            B_[nf_] = *(const ushort8*)(wpb + \
                (size_t)(((t) * 16 + nfgB + nf_) * 64) * 8); \
    } while (0)

    #define TILE(t, BC, BN) do { \
        if ((t) + 1 < NT) { \
            STAGE((t) + 1); \
            __builtin_amdgcn_sched_barrier(0); \
            LOADB(BN, (t) + 1); \
            __builtin_amdgcn_sched_barrier(0); \
        } \
        const char* L_ = &lds[(t) & 1][0]; \
        ushort8 a_[8]; \
        _Pragma("unroll") for (int mf_ = 0; mf_ < 8; ++mf_) \
            a_[mf_] = *(const ushort8*)(L_ + aB + mf_ * 1024); \
        __builtin_amdgcn_s_setprio(1); \
        _Pragma("unroll") for (int mf_ = 0; mf_ < 8; ++mf_) \
            _Pragma("unroll") for (int nf_ = 0; nf_ < 4; ++nf_) \
                acc[mf_][nf_] = __builtin_amdgcn_mfma_f32_16x16x32_bf16( \
                    __builtin_bit_cast(bf16x8, BC[nf_]), \
                    __builtin_bit_cast(bf16x8, a_[mf_]), \
                    acc[mf_][nf_], 0, 0, 0); \
        __builtin_amdgcn_s_setprio(0); \
        if ((t) + 1 < NT) \
            asm volatile("s_waitcnt vmcnt(0)" ::: "memory"); \
        __builtin_amdgcn_s_barrier(); \
    } while (0)

    // ---- prologue ----
    STAGE(0);
    LOADB(b0r, 0);
    asm volatile("s_waitcnt vmcnt(0)" ::: "memory");
    __builtin_amdgcn_s_barrier();

    #pragma unroll 1
    for (int tt = 0; tt < NT; tt += 2) {        // static ping-pong (rule #20)
        TILE(tt, b0r, b1r);
        TILE(tt + 1, b1r, b0r);
    }

    // ---- epilogue: direct stores; D row=co, col=m; lanes 0-15 contiguous in w
    const int mwave = m0 + wm0;
    const int co0 = n0 + wn0 + (fg << 2);
    #pragma unroll
    for (int mf = 0; mf < 8; ++mf) {
        int m = mwave + mf * 16 + fr;
        int n = m / IMGHW;
        int hwr = m - n * IMGHW;
        uint32_t basem = (uint32_t)(n * (CO_ * IMGHW) + hwr);
        #pragma unroll
        for (int nf = 0; nf < 4; ++nf)
            #pragma unroll
            for (int q = 0; q < 4; ++q)
                out[basem + (uint32_t)(co0 + nf * 16 + q) * IMGHW] = acc[mf][nf][q];
    }
    #undef LOADB
    #undef TILE
}

// ================= fallback (round-1 kernel, used if ws too small) ==========
#define BM    64
#define BK    32
#define NSTEP 36
#define LDSP  40

template<bool PACKED>
__global__ __launch_bounds__(256, 2)
void conv_fb(const float* __restrict__ x,
             const float* __restrict__ wraw,
             const unsigned short* __restrict__ wp,
             float* __restrict__ out)
{
    __shared__ __align__(16) unsigned short Al[2][BM][LDSP];
    __shared__ __align__(16) unsigned short Bl[2][CO_][LDSP];

    const int tid  = threadIdx.x;
    const int lane = tid & 63;
    const int wid  = tid >> 6;

    const int mb    = blockIdx.x;
    const int n_img = mb / 49;
    const int hw0   = (mb - n_img * 49) * BM;

    const int mm = lane;
    const int hw = hw0 + mm;
    const int h  = hw / HW_;
    const int w_ = hw - h * HW_;

    const int bco  = tid >> 2;
    const int bkkg = tid & 3;

    float   aPF[8];
    ushort8 bPF[4];

    auto loadA = [&](int step) {
        int khkw = step >> 2;
        int kh = khkw / 3, kw = khkw - (khkw / 3) * 3;
        int ci0 = (step & 3) * BK + wid * 8;
        int ih = h + kh - 1, iw = w_ + kw - 1;
        bool valid = ((unsigned)ih < (unsigned)HW_) && ((unsigned)iw < (unsigned)HW_);
        const float* px = x + (((size_t)(n_img * CIN + ci0) * HW_ + ih) * HW_ + iw);
        #pragma unroll
        for (int e = 0; e < 8; ++e)
            aPF[e] = valid ? px[e * IMGHW] : 0.f;
    };
    auto writeA = [&](int buf) {
        ushort8 v;
        #pragma unroll
        for (int e = 0; e < 8; ++e) v[e] = f2bf(aPF[e]);
        *(ushort8*)&Al[buf][mm][wid * 8] = v;
    };
    auto loadB = [&](int step) {
        int khkw = step >> 2;
        int ci0 = (step & 3) * BK + bkkg * 8;
        #pragma unroll
        for (int r = 0; r < 4; ++r) {
            int co = r * 64 + bco;
            ushort8 v;
            #pragma unroll
            for (int e = 0; e < 8; ++e)
                v[e] = f2bf(wraw[(co * CIN + ci0 + e) * 9 + khkw]);
            bPF[r] = v;
        }
    };
    auto writeB = [&](int buf) {
        #pragma unroll
        for (int r = 0; r < 4; ++r)
            *(ushort8*)&Bl[buf][r * 64 + bco][bkkg * 8] = bPF[r];
    };

    f32x4 acc[4][4];
    #pragma unroll
    for (int i = 0; i < 4; ++i)
        #pragma unroll
        for (int j = 0; j < 4; ++j)
            acc[i][j] = (f32x4){0.f, 0.f, 0.f, 0.f};

    const int frow = lane & 15;
    const int fk   = (lane >> 4) * 8;

    loadA(0); loadB(0);
    writeA(0); writeB(0);
    __syncthreads();

    for (int s = 0; s < NSTEP; ++s) {
        const int cur = s & 1;
        if (s + 1 < NSTEP) { loadA(s + 1); loadB(s + 1); }

        ushort8 aF[4], bF[4];
        #pragma unroll
        for (int i = 0; i < 4; ++i)
            aF[i] = *(const ushort8*)&Bl[cur][wid * 64 + i * 16 + frow][fk];
        #pragma unroll
        for (int j = 0; j < 4; ++j)
            bF[j] = *(const ushort8*)&Al[cur][j * 16 + frow][fk];

        #pragma unroll
        for (int i = 0; i < 4; ++i)
            #pragma unroll
            for (int j = 0; j < 4; ++j)
                acc[i][j] = __builtin_amdgcn_mfma_f32_16x16x32_bf16(
                    __builtin_bit_cast(bf16x8, aF[i]),
                    __builtin_bit_cast(bf16x8, bF[j]),
                    acc[i][j], 0, 0, 0);

        if (s + 1 < NSTEP) { writeA(cur ^ 1); writeB(cur ^ 1); }
        __syncthreads();
    }

    float* ob = out + (size_t)n_img * (CO_ * IMGHW) + hw0;
    #pragma unroll
    for (int i = 0; i < 4; ++i) {
        int co0 = wid * 64 + i * 16 + (lane >> 4) * 4;
        #pragma unroll
        for (int j = 0; j < 4; ++j) {
            int mcol = j * 16 + (lane & 15);
            #pragma unroll
            for (int q = 0; q < 4; ++q)
                ob[(size_t)(co0 + q) * IMGHW + mcol] = acc[i][j][q];
        }
    }
}

extern "C" void kernel_launch(void* const* d_in, const int* in_sizes, int n_in,
                              void* d_out, int out_size, void* d_ws, size_t ws_size,
                              hipStream_t stream) {
    (void)in_sizes; (void)n_in; (void)out_size;
    const float* x  = (const float*)d_in[0];
    const float* wt = (const float*)d_in[1];
    float* out = (float*)d_out;

    if (ws_size >= WS_NEED) {
        unsigned short* xt  = (unsigned short*)d_ws;
        unsigned short* wp2 = (unsigned short*)((char*)d_ws + XT_BYTES);
        prep<<<XBLKS + PBLKS, 256, 0, stream>>>(x, xt, wt, wp2);
        conv14<<<784, 256, 0, stream>>>(xt, wp2, out);
    } else {
        conv_fb<false><<<100352 / BM, 256, 0, stream>>>(x, wt, nullptr, out);
    }
}